// Round 1
// baseline (649.235 us; speedup 1.0000x reference)
//
#include <hip/hip_runtime.h>

// Problem constants: H=8, B=16, G=512, NQ=512, D=512, KD=VD=64, E=512, NORM=0.125
using u8 = unsigned char;
using u16 = unsigned short;
using u32 = unsigned int;

typedef __attribute__((ext_vector_type(8))) __bf16 bf16x8;
typedef __attribute__((ext_vector_type(4))) float f32x4;

#define MFMA16(A, B, C) __builtin_amdgcn_mfma_f32_16x16x32_bf16((A), (B), (C), 0, 0, 0)

__device__ __forceinline__ u16 f2bf(float f) {
  u32 u = __builtin_bit_cast(u32, f);
  u += 0x7fffu + ((u >> 16) & 1u);   // round-to-nearest-even
  return (u16)(u >> 16);
}

// ---------------------------------------------------------------- prep kernels

__global__ void prep_q_k(const float* __restrict__ q, u16* __restrict__ qb) {
  int idx = blockIdx.x * 256 + threadIdx.x;          // one per 8 elems
  const float4* p = (const float4*)q + (size_t)idx * 2;
  float4 a = p[0], b = p[1];
  u32 w0 = f2bf(a.x) | ((u32)f2bf(a.y) << 16);
  u32 w1 = f2bf(a.z) | ((u32)f2bf(a.w) << 16);
  u32 w2 = f2bf(b.x) | ((u32)f2bf(b.y) << 16);
  u32 w3 = f2bf(b.z) | ((u32)f2bf(b.w) << 16);
  ((uint4*)qb)[idx] = make_uint4(w0, w1, w2, w3);
}

struct WPtrs { const float* w[12]; };

// Wbt[col][d] = W_iw[h][d][kk],  col = iw*512 + h*64 + kk  (K-major for B-fragments)
__global__ void prep_w_k(WPtrs wp, u16* __restrict__ Wbt) {
  int iw = blockIdx.x >> 3;
  int h  = blockIdx.x & 7;
  int kk = threadIdx.x & 63;
  int dd = threadIdx.x >> 6;
  const float* W = wp.w[iw];
  for (int d = dd; d < 512; d += 4) {
    float v = W[((size_t)(h * 512 + d)) * 64 + kk];      // coalesced over kk
    Wbt[((size_t)(iw * 512 + h * 64 + kk)) * 512 + d] = f2bf(v);
  }
}

// Wot[h][e][v] = W_out[h][v][e]
__global__ void prep_wout_k(const float* __restrict__ wout, u16* __restrict__ Wot) {
  int h = blockIdx.x;
  int t = threadIdx.x;
  for (int ee = 0; ee < 2; ee++) {
    int e = ee * 256 + t;
    for (int v = 0; v < 64; v++)
      Wot[((size_t)(h * 512 + e)) * 64 + v] = f2bf(wout[((size_t)(h * 64 + v)) * 512 + e]);
  }
}

// Mpk[b][q][c][g] (uint8 0/1): c0=sparse_dist[b,q,g], c1=att[b,g,q], c2=att[b,q,g], c3=group[b,q,g]
__global__ void prep_masks_k(const int* __restrict__ att, const int* __restrict__ grp,
                             const int* __restrict__ sd, u8* __restrict__ Mpk) {
  int idx = blockIdx.x * 256 + threadIdx.x;  // one per (b,q,4g)
  int g0 = (idx & 127) << 2;
  int q  = (idx >> 7) & 511;
  int b  = idx >> 16;
  size_t rbase = ((size_t)(b * 512 + q)) * 512 + g0;
  int4 v0 = *(const int4*)(sd + rbase);
  int4 v2 = *(const int4*)(att + rbase);
  int4 v3 = *(const int4*)(grp + rbase);
  size_t cb = ((size_t)(b * 512 + g0)) * 512 + q;     // att[b][g][q], strided
  int t0 = att[cb], t1 = att[cb + 512], t2 = att[cb + 1024], t3 = att[cb + 1536];
  size_t ob = (((size_t)(b * 512 + q)) * 4) * 512 + g0;
  auto pk = [](int a, int b2, int c, int d) -> u32 {
    return (a ? 1u : 0u) | ((b2 ? 1u : 0u) << 8) | ((c ? 1u : 0u) << 16) | ((d ? 1u : 0u) << 24);
  };
  *(u32*)(Mpk + ob)        = pk(v0.x, v0.y, v0.z, v0.w);
  *(u32*)(Mpk + ob + 512)  = pk(t0, t1, t2, t3);
  *(u32*)(Mpk + ob + 1024) = pk(v2.x, v2.y, v2.z, v2.w);
  *(u32*)(Mpk + ob + 1536) = pk(v3.x, v3.y, v3.z, v3.w);
}

// ---------------------------------------------------------------- pass A: all 12 projections
// C(8192 x 6144) = qb(8192 x 512) * W(512 x 6144). 128x128 tile, BK=64, 4 waves.
// Q/K classes stored [ihb][n][k]; V class stored transposed [ihb][k][n].
__global__ __launch_bounds__(256) void gemm_proj_k(const u16* __restrict__ qb,
                                                   const u16* __restrict__ Wbt,
                                                   u16* __restrict__ P) {
  __shared__ u16 As[128][72];
  __shared__ u16 Bs[128][72];
  int t = threadIdx.x;
  int wave = t >> 6, lane = t & 63, quad = lane >> 4, l16 = lane & 15;
  int m0w = (wave >> 1) * 64, n0w = (wave & 1) * 64;
  int bm = blockIdx.x, bn = blockIdx.y;
  f32x4 acc[4][4] = {};
  int sr = t >> 1;
  int sseg = (t & 1) * 32;
  const u16* ag = qb  + ((size_t)(bm * 128 + sr)) * 512 + sseg;
  const u16* bg = Wbt + ((size_t)(bn * 128 + sr)) * 512 + sseg;
  for (int k0 = 0; k0 < 512; k0 += 64) {
    uint4 av[4], bv[4];
#pragma unroll
    for (int j = 0; j < 4; j++) {
      av[j] = *(const uint4*)(ag + k0 + j * 8);
      bv[j] = *(const uint4*)(bg + k0 + j * 8);
    }
    __syncthreads();
#pragma unroll
    for (int j = 0; j < 4; j++) {
      *(uint4*)&As[sr][sseg + j * 8] = av[j];
      *(uint4*)&Bs[sr][sseg + j * 8] = bv[j];
    }
    __syncthreads();
#pragma unroll
    for (int kc = 0; kc < 2; kc++) {
      bf16x8 am[4], bnf[4];
#pragma unroll
      for (int i = 0; i < 4; i++) {
        am[i]  = *(const bf16x8*)&As[m0w + i * 16 + l16][kc * 32 + quad * 8];
        bnf[i] = *(const bf16x8*)&Bs[n0w + i * 16 + l16][kc * 32 + quad * 8];
      }
#pragma unroll
      for (int mt = 0; mt < 4; mt++)
#pragma unroll
        for (int nt = 0; nt < 4; nt++)
          acc[mt][nt] = MFMA16(am[mt], bnf[nt], acc[mt][nt]);
    }
  }
#pragma unroll
  for (int nt = 0; nt < 4; nt++) {
    int col = bn * 128 + n0w + nt * 16 + l16;
    int iw = col >> 9;
    int h  = (col >> 6) & 7;
    int k  = col & 63;
    bool isV = (iw % 3) == 2;
    size_t blk = ((size_t)(iw * 8 + h)) * 16;
#pragma unroll
    for (int mt = 0; mt < 4; mt++) {
      int mrow = bm * 128 + m0w + mt * 16 + quad * 4;
#pragma unroll
      for (int r = 0; r < 4; r++) {
        int m = mrow + r;
        int b = m >> 9, n = m & 511;
        size_t idx = isV ? (((blk + b) * 64 + k) * 512 + n)
                         : (((blk + b) * 512 + n) * 64 + k);
        P[idx] = f2bf(acc[mt][nt][r]);
      }
    }
  }
}

// ---------------------------------------------------------------- pass B: fused masked attention
// grid (qt=8, b=16, h=8); block 256 = 4 waves, each wave owns 16 q-rows. Flash online softmax.
__global__ __launch_bounds__(256) void attn_k(const u16* __restrict__ P,
                                              const u8* __restrict__ Mpk,
                                              u16* __restrict__ heads) {
  __shared__ u16 Qs[64][72];
  __shared__ u16 Ks[64][72];
  __shared__ u16 Vs[64][72];   // [v][g]
  __shared__ u16 Ps[64][72];
  __shared__ u8  Ms[64][64];
  int t = threadIdx.x;
  int wave = t >> 6, lane = t & 63, quad = lane >> 4, l16 = lane & 15;
  int qt = blockIdx.x, b = blockIdx.y, h = blockIdx.z;
  int q0 = qt * 64;
  float mrow[4], lrow[4];
  f32x4 O[4] = {};
#pragma unroll
  for (int r = 0; r < 4; r++) { mrow[r] = -1e30f; lrow[r] = 0.f; }
  int sr = t >> 2;
  int ss = (t & 3) * 16;
  for (int c = 0; c < 4; c++) {
    const u16* PQ = P + ((size_t)((3 * c + 0) * 8 + h) * 16 + b) * 32768;
    const u16* PK = P + ((size_t)((3 * c + 1) * 8 + h) * 16 + b) * 32768;
    const u16* PV = P + ((size_t)((3 * c + 2) * 8 + h) * 16 + b) * 32768;  // [v][n]
    {
      uint4 x0 = *(const uint4*)(PQ + (size_t)(q0 + sr) * 64 + ss);
      uint4 x1 = *(const uint4*)(PQ + (size_t)(q0 + sr) * 64 + ss + 8);
      *(uint4*)&Qs[sr][ss]     = x0;    // safe: prior c-iter ended with __syncthreads
      *(uint4*)&Qs[sr][ss + 8] = x1;
    }
    for (int gt = 0; gt < 8; gt++) {
      int g0 = gt * 64;
      uint4 kv0 = *(const uint4*)(PK + (size_t)(g0 + sr) * 64 + ss);
      uint4 kv1 = *(const uint4*)(PK + (size_t)(g0 + sr) * 64 + ss + 8);
      uint4 vv0 = *(const uint4*)(PV + (size_t)sr * 512 + g0 + ss);
      uint4 vv1 = *(const uint4*)(PV + (size_t)sr * 512 + g0 + ss + 8);
      uint4 mv  = *(const uint4*)(Mpk + (((size_t)(b * 512 + q0 + sr) * 4 + c) * 512 + g0 + (t & 3) * 16));
      __syncthreads();   // prior iter's LDS reads done before overwrite
      *(uint4*)&Ks[sr][ss]     = kv0;
      *(uint4*)&Ks[sr][ss + 8] = kv1;
      *(uint4*)&Vs[sr][ss]     = vv0;
      *(uint4*)&Vs[sr][ss + 8] = vv1;
      *(uint4*)&Ms[sr][(t & 3) * 16] = mv;
      __syncthreads();
      bf16x8 aq0 = *(const bf16x8*)&Qs[wave * 16 + l16][quad * 8];
      bf16x8 aq1 = *(const bf16x8*)&Qs[wave * 16 + l16][32 + quad * 8];
      f32x4 S[4];
#pragma unroll
      for (int nt = 0; nt < 4; nt++) {
        bf16x8 bk0 = *(const bf16x8*)&Ks[nt * 16 + l16][quad * 8];
        bf16x8 bk1 = *(const bf16x8*)&Ks[nt * 16 + l16][32 + quad * 8];
        f32x4 sa = {};
        sa = MFMA16(aq0, bk0, sa);
        sa = MFMA16(aq1, bk1, sa);
        S[nt] = sa;
      }
#pragma unroll
      for (int nt = 0; nt < 4; nt++)
#pragma unroll
        for (int r = 0; r < 4; r++) {
          u8 mk = Ms[wave * 16 + quad * 4 + r][nt * 16 + l16];
          float sv = S[nt][r] * 0.125f;            // NORM = 1/sqrt(64)
          S[nt][r] = mk ? sv : -1e30f;             // sentinel for masked
        }
      float mnew[4], alpha[4];
#pragma unroll
      for (int r = 0; r < 4; r++) {
        float rm = fmaxf(fmaxf(S[0][r], S[1][r]), fmaxf(S[2][r], S[3][r]));
        rm = fmaxf(rm, __shfl_xor(rm, 1));
        rm = fmaxf(rm, __shfl_xor(rm, 2));
        rm = fmaxf(rm, __shfl_xor(rm, 4));
        rm = fmaxf(rm, __shfl_xor(rm, 8));
        float mn = fmaxf(mrow[r], rm);
        mnew[r] = mn;
        alpha[r] = __expf(mrow[r] - mn);           // exp(0)=1 when both -1e30: fine
        mrow[r] = mn;
      }
#pragma unroll
      for (int nt = 0; nt < 4; nt++)
#pragma unroll
        for (int r = 0; r < 4; r++) {
          float sv = S[nt][r];
          S[nt][r] = (sv < -1e29f) ? 0.f : __expf(sv - mnew[r]);  // masked -> exactly 0
        }
#pragma unroll
      for (int r = 0; r < 4; r++) {
        float rs = S[0][r] + S[1][r] + S[2][r] + S[3][r];
        rs += __shfl_xor(rs, 1);
        rs += __shfl_xor(rs, 2);
        rs += __shfl_xor(rs, 4);
        rs += __shfl_xor(rs, 8);
        lrow[r] = lrow[r] * alpha[r] + rs;
      }
#pragma unroll
      for (int vt = 0; vt < 4; vt++)
#pragma unroll
        for (int r = 0; r < 4; r++) O[vt][r] *= alpha[r];
      // C-layout -> A-layout round trip through LDS (wave-private rows, no barrier)
#pragma unroll
      for (int nt = 0; nt < 4; nt++)
#pragma unroll
        for (int r = 0; r < 4; r++)
          Ps[wave * 16 + quad * 4 + r][nt * 16 + l16] = f2bf(S[nt][r]);
#pragma unroll
      for (int kc = 0; kc < 2; kc++) {
        bf16x8 ap = *(const bf16x8*)&Ps[wave * 16 + l16][kc * 32 + quad * 8];
#pragma unroll
        for (int vt = 0; vt < 4; vt++) {
          bf16x8 bv = *(const bf16x8*)&Vs[vt * 16 + l16][kc * 32 + quad * 8];
          O[vt] = MFMA16(ap, bv, O[vt]);
        }
      }
    }
    __syncthreads();  // protect Qs restage of next c
  }
#pragma unroll
  for (int vt = 0; vt < 4; vt++)
#pragma unroll
    for (int r = 0; r < 4; r++) {
      float l = lrow[r];
      float val = (l > 0.f) ? O[vt][r] / l : 0.f;
      heads[((size_t)(h * 16 + b) * 512 + q0 + wave * 16 + quad * 4 + r) * 64 + vt * 16 + l16] = f2bf(val);
    }
}

// ---------------------------------------------------------------- pass C: out = heads x W_out
// out(8192 x 512) = heads[(b,q),(h,v)=512] * Wot. 64x64 tile, K-loop over h.
__global__ __launch_bounds__(256) void gemm_out_k(const u16* __restrict__ heads,
                                                  const u16* __restrict__ Wot,
                                                  float* __restrict__ out) {
  __shared__ u16 As[64][72];
  __shared__ u16 Bs[64][72];
  int t = threadIdx.x;
  int wave = t >> 6, lane = t & 63, quad = lane >> 4, l16 = lane & 15;
  int m0 = blockIdx.x * 64, e0 = blockIdx.y * 64;
  int b = m0 >> 9, q0 = m0 & 511;
  f32x4 acc[4] = {};
  int sr = t >> 2, ss = (t & 3) * 16;
  for (int h = 0; h < 8; h++) {
    uint4 a0 = *(const uint4*)(heads + ((size_t)(h * 16 + b) * 512 + q0 + sr) * 64 + ss);
    uint4 a1 = *(const uint4*)(heads + ((size_t)(h * 16 + b) * 512 + q0 + sr) * 64 + ss + 8);
    uint4 b0 = *(const uint4*)(Wot + ((size_t)(h * 512 + e0 + sr)) * 64 + ss);
    uint4 b1 = *(const uint4*)(Wot + ((size_t)(h * 512 + e0 + sr)) * 64 + ss + 8);
    __syncthreads();
    *(uint4*)&As[sr][ss]     = a0;
    *(uint4*)&As[sr][ss + 8] = a1;
    *(uint4*)&Bs[sr][ss]     = b0;
    *(uint4*)&Bs[sr][ss + 8] = b1;
    __syncthreads();
#pragma unroll
    for (int kc = 0; kc < 2; kc++) {
      bf16x8 af = *(const bf16x8*)&As[wave * 16 + l16][kc * 32 + quad * 8];
#pragma unroll
      for (int nt = 0; nt < 4; nt++) {
        bf16x8 bfr = *(const bf16x8*)&Bs[nt * 16 + l16][kc * 32 + quad * 8];
        acc[nt] = MFMA16(af, bfr, acc[nt]);
      }
    }
  }
#pragma unroll
  for (int nt = 0; nt < 4; nt++)
#pragma unroll
    for (int r = 0; r < 4; r++)
      out[((size_t)(b * 512 + q0 + wave * 16 + quad * 4 + r)) * 512 + e0 + nt * 16 + l16] = acc[nt][r];
}

// ---------------------------------------------------------------- launch

extern "C" void kernel_launch(void* const* d_in, const int* in_sizes, int n_in,
                              void* d_out, int out_size, void* d_ws, size_t ws_size,
                              hipStream_t stream) {
  const float* q   = (const float*)d_in[0];
  const int*   att = (const int*)d_in[1];
  const int*   grp = (const int*)d_in[2];
  const int*   sd  = (const int*)d_in[3];
  WPtrs wp;
  for (int j = 0; j < 12; j++) wp.w[j] = (const float*)d_in[4 + j];
  const float* wout = (const float*)d_in[16];

  char* ws = (char*)d_ws;
  // workspace layout (total 141,033,472 B)
  u16* qb    = (u16*)(ws + 0);            //   8,388,608
  u16* Wbt   = (u16*)(ws + 8388608);      //   6,291,456
  u16* Wot   = (u16*)(ws + 14680064);     //     524,288
  u8*  Mpk   = (u8*) (ws + 15204352);     //  16,777,216
  u16* P     = (u16*)(ws + 31981568);     // 100,663,296
  u16* heads = (u16*)(ws + 132644864);    //   8,388,608
  float* out = (float*)d_out;

  prep_masks_k<<<4096, 256, 0, stream>>>(att, grp, sd, Mpk);
  prep_q_k<<<2048, 256, 0, stream>>>(q, qb);
  prep_w_k<<<96, 256, 0, stream>>>(wp, Wbt);
  prep_wout_k<<<8, 256, 0, stream>>>(wout, Wot);
  gemm_proj_k<<<dim3(64, 48), 256, 0, stream>>>(qb, Wbt, P);
  attn_k<<<dim3(8, 16, 8), 256, 0, stream>>>(P, Mpk, heads);
  gemm_out_k<<<dim3(128, 8), 256, 0, stream>>>(heads, Wot, out);
}

// Round 2
// 618.278 us; speedup vs baseline: 1.0501x; 1.0501x over previous
//
#include <hip/hip_runtime.h>

// Problem constants: H=8, B=16, G=512, NQ=512, D=512, KD=VD=64, E=512, NORM=0.125
using u8 = unsigned char;
using u16 = unsigned short;
using u32 = unsigned int;

typedef __attribute__((ext_vector_type(8))) __bf16 bf16x8;
typedef __attribute__((ext_vector_type(4))) float f32x4;

#define MFMA16(A, B, C) __builtin_amdgcn_mfma_f32_16x16x32_bf16((A), (B), (C), 0, 0, 0)

__device__ __forceinline__ u16 f2bf(float f) {
  u32 u = __builtin_bit_cast(u32, f);
  u += 0x7fffu + ((u >> 16) & 1u);   // round-to-nearest-even
  return (u16)(u >> 16);
}

// ---------------------------------------------------------------- prep kernels

__global__ void prep_q_k(const float* __restrict__ q, u16* __restrict__ qb) {
  int idx = blockIdx.x * 256 + threadIdx.x;          // one per 8 elems
  const float4* p = (const float4*)q + (size_t)idx * 2;
  float4 a = p[0], b = p[1];
  u32 w0 = f2bf(a.x) | ((u32)f2bf(a.y) << 16);
  u32 w1 = f2bf(a.z) | ((u32)f2bf(a.w) << 16);
  u32 w2 = f2bf(b.x) | ((u32)f2bf(b.y) << 16);
  u32 w3 = f2bf(b.z) | ((u32)f2bf(b.w) << 16);
  ((uint4*)qb)[idx] = make_uint4(w0, w1, w2, w3);
}

struct WPtrs { const float* w[12]; };

// Wbt[col][d] = W_iw[h][d][kk],  col = iw*512 + h*64 + kk  (K-major for B-fragments)
__global__ void prep_w_k(WPtrs wp, u16* __restrict__ Wbt) {
  int iw = blockIdx.x >> 3;
  int h  = blockIdx.x & 7;
  int kk = threadIdx.x & 63;
  int dd = threadIdx.x >> 6;
  const float* W = wp.w[iw];
  for (int d = dd; d < 512; d += 4) {
    float v = W[((size_t)(h * 512 + d)) * 64 + kk];      // coalesced over kk
    Wbt[((size_t)(iw * 512 + h * 64 + kk)) * 512 + d] = f2bf(v);
  }
}

// Wot[h][e][v] = W_out[h][v][e]
__global__ void prep_wout_k(const float* __restrict__ wout, u16* __restrict__ Wot) {
  int h = blockIdx.x;
  int t = threadIdx.x;
  for (int ee = 0; ee < 2; ee++) {
    int e = ee * 256 + t;
    for (int v = 0; v < 64; v++)
      Wot[((size_t)(h * 512 + e)) * 64 + v] = f2bf(wout[((size_t)(h * 64 + v)) * 512 + e]);
  }
}

// Mpk[b][q][c][g] (uint8 0/1): c0=sparse_dist[b,q,g], c1=att[b,g,q], c2=att[b,q,g], c3=group[b,q,g]
__global__ void prep_masks_k(const int* __restrict__ att, const int* __restrict__ grp,
                             const int* __restrict__ sd, u8* __restrict__ Mpk) {
  int idx = blockIdx.x * 256 + threadIdx.x;  // one per (b,q,4g)
  int g0 = (idx & 127) << 2;
  int q  = (idx >> 7) & 511;
  int b  = idx >> 16;
  size_t rbase = ((size_t)(b * 512 + q)) * 512 + g0;
  int4 v0 = *(const int4*)(sd + rbase);
  int4 v2 = *(const int4*)(att + rbase);
  int4 v3 = *(const int4*)(grp + rbase);
  size_t cb = ((size_t)(b * 512 + g0)) * 512 + q;     // att[b][g][q], strided
  int t0 = att[cb], t1 = att[cb + 512], t2 = att[cb + 1024], t3 = att[cb + 1536];
  size_t ob = (((size_t)(b * 512 + q)) * 4) * 512 + g0;
  auto pk = [](int a, int b2, int c, int d) -> u32 {
    return (a ? 1u : 0u) | ((b2 ? 1u : 0u) << 8) | ((c ? 1u : 0u) << 16) | ((d ? 1u : 0u) << 24);
  };
  *(u32*)(Mpk + ob)        = pk(v0.x, v0.y, v0.z, v0.w);
  *(u32*)(Mpk + ob + 512)  = pk(t0, t1, t2, t3);
  *(u32*)(Mpk + ob + 1024) = pk(v2.x, v2.y, v2.z, v2.w);
  *(u32*)(Mpk + ob + 1536) = pk(v3.x, v3.y, v3.z, v3.w);
}

// ---------------------------------------------------------------- pass A: all 12 projections
// C(8192 x 6144) = qb(8192 x 512) * W(512 x 6144). 128x128 tile, BK=64, 4 waves.
// Q/K classes stored [ihb][n][k]; V class stored transposed [ihb][k][n].
// Epilogue stages C through LDS (V-class: transposed) for coalesced uint4 stores.
__global__ __launch_bounds__(256) void gemm_proj_k(const u16* __restrict__ qb,
                                                   const u16* __restrict__ Wbt,
                                                   u16* __restrict__ P) {
  __shared__ u16 smem[2 * 128 * 72];                 // As | Bs; reused as Cs in epilogue
  u16 (*As)[72] = (u16(*)[72])smem;
  u16 (*Bs)[72] = (u16(*)[72])(smem + 128 * 72);
  int t = threadIdx.x;
  int wave = t >> 6, lane = t & 63, quad = lane >> 4, l16 = lane & 15;
  int m0w = (wave >> 1) * 64, n0w = (wave & 1) * 64;
  int bm = blockIdx.x, bn = blockIdx.y;
  f32x4 acc[4][4] = {};
  int sr = t >> 1;
  int sseg = (t & 1) * 32;
  const u16* ag = qb  + ((size_t)(bm * 128 + sr)) * 512 + sseg;
  const u16* bg = Wbt + ((size_t)(bn * 128 + sr)) * 512 + sseg;
  for (int k0 = 0; k0 < 512; k0 += 64) {
    uint4 av[4], bv[4];
#pragma unroll
    for (int j = 0; j < 4; j++) {
      av[j] = *(const uint4*)(ag + k0 + j * 8);
      bv[j] = *(const uint4*)(bg + k0 + j * 8);
    }
    __syncthreads();
#pragma unroll
    for (int j = 0; j < 4; j++) {
      *(uint4*)&As[sr][sseg + j * 8] = av[j];
      *(uint4*)&Bs[sr][sseg + j * 8] = bv[j];
    }
    __syncthreads();
#pragma unroll
    for (int kc = 0; kc < 2; kc++) {
      bf16x8 am[4], bnf[4];
#pragma unroll
      for (int i = 0; i < 4; i++) {
        am[i]  = *(const bf16x8*)&As[m0w + i * 16 + l16][kc * 32 + quad * 8];
        bnf[i] = *(const bf16x8*)&Bs[n0w + i * 16 + l16][kc * 32 + quad * 8];
      }
#pragma unroll
      for (int mt = 0; mt < 4; mt++)
#pragma unroll
        for (int nt = 0; nt < 4; nt++)
          acc[mt][nt] = MFMA16(am[mt], bnf[nt], acc[mt][nt]);
    }
  }
  // ---------------- epilogue: LDS-staged coalesced stores ----------------
  // Both 64-col groups of this block share iw (bn*2 and bn*2+1 have equal >>3),
  // so the whole block is one class.
  int iw = (bn * 2) >> 3;
  bool isV = (iw % 3) == 2;
  int b  = bm >> 2;              // 4 row-blocks per batch element (512/128)
  int n0 = (bm & 3) * 128;
  u16 (*Cs)[136] = (u16(*)[136])smem;  // 128 x 136 u16 = 34816 B <= 36864 B
  __syncthreads();               // all waves done reading As/Bs
#pragma unroll
  for (int mt = 0; mt < 4; mt++)
#pragma unroll
    for (int nt = 0; nt < 4; nt++)
#pragma unroll
      for (int r = 0; r < 4; r++) {
        int rm = m0w + mt * 16 + quad * 4 + r;
        int cn = n0w + nt * 16 + l16;
        u16 v = f2bf(acc[mt][nt][r]);
        if (!isV) Cs[rm][cn] = v;      // row = m, col = k
        else      Cs[cn][rm] = v;      // transposed: row = k, col = m
      }
  __syncthreads();
  // Unified store phase: row-major uint4 reads from Cs, contiguous global bursts.
#pragma unroll
  for (int p = 0; p < 8; p++) {
    int idx = p * 256 + t;
    int seg  = idx & 15;         // 16B chunk within Cs row
    int crow = idx >> 4;         // 0..127
    uint4 v = *(const uint4*)&Cs[crow][seg * 8];
    if (!isV) {
      // crow = m-row, chunk = k (spans both col groups; 8 | 64 so no straddle)
      int col = seg * 8;
      int cg = col >> 6, k = col & 63;
      int h = (bn * 2 + cg) & 7;
      u16* dst = P + ((size_t)((iw * 8 + h) * 16 + b)) * 32768 + (size_t)(n0 + crow) * 64 + k;
      *(uint4*)dst = v;          // lanes: 2 groups of 8 -> 128 B bursts
    } else {
      // crow = global col (k within group), chunk = 8 consecutive m's
      int cg = crow >> 6, k = crow & 63;
      int h = (bn * 2 + cg) & 7;
      u16* dst = P + ((size_t)((iw * 8 + h) * 16 + b)) * 32768 + (size_t)k * 512 + n0 + seg * 8;
      *(uint4*)dst = v;          // 16 lanes -> 256 B contiguous
    }
  }
}

// ---------------------------------------------------------------- pass B: fused masked attention
// grid (qt=8, b=16, h=8); block 256 = 4 waves, each wave owns 16 q-rows. Flash online softmax.
__global__ __launch_bounds__(256) void attn_k(const u16* __restrict__ P,
                                              const u8* __restrict__ Mpk,
                                              u16* __restrict__ heads) {
  __shared__ u16 Qs[64][72];
  __shared__ u16 Ks[64][72];
  __shared__ u16 Vs[64][72];   // [v][g]
  __shared__ u16 Ps[64][72];
  __shared__ u8  Ms[64][64];
  int t = threadIdx.x;
  int wave = t >> 6, lane = t & 63, quad = lane >> 4, l16 = lane & 15;
  int qt = blockIdx.x, b = blockIdx.y, h = blockIdx.z;
  int q0 = qt * 64;
  float mrow[4], lrow[4];
  f32x4 O[4] = {};
#pragma unroll
  for (int r = 0; r < 4; r++) { mrow[r] = -1e30f; lrow[r] = 0.f; }
  int sr = t >> 2;
  int ss = (t & 3) * 16;
  for (int c = 0; c < 4; c++) {
    const u16* PQ = P + ((size_t)((3 * c + 0) * 8 + h) * 16 + b) * 32768;
    const u16* PK = P + ((size_t)((3 * c + 1) * 8 + h) * 16 + b) * 32768;
    const u16* PV = P + ((size_t)((3 * c + 2) * 8 + h) * 16 + b) * 32768;  // [v][n]
    {
      uint4 x0 = *(const uint4*)(PQ + (size_t)(q0 + sr) * 64 + ss);
      uint4 x1 = *(const uint4*)(PQ + (size_t)(q0 + sr) * 64 + ss + 8);
      *(uint4*)&Qs[sr][ss]     = x0;    // safe: prior c-iter ended with __syncthreads
      *(uint4*)&Qs[sr][ss + 8] = x1;
    }
    for (int gt = 0; gt < 8; gt++) {
      int g0 = gt * 64;
      uint4 kv0 = *(const uint4*)(PK + (size_t)(g0 + sr) * 64 + ss);
      uint4 kv1 = *(const uint4*)(PK + (size_t)(g0 + sr) * 64 + ss + 8);
      uint4 vv0 = *(const uint4*)(PV + (size_t)sr * 512 + g0 + ss);
      uint4 vv1 = *(const uint4*)(PV + (size_t)sr * 512 + g0 + ss + 8);
      uint4 mv  = *(const uint4*)(Mpk + (((size_t)(b * 512 + q0 + sr) * 4 + c) * 512 + g0 + (t & 3) * 16));
      __syncthreads();   // prior iter's LDS reads done before overwrite
      *(uint4*)&Ks[sr][ss]     = kv0;
      *(uint4*)&Ks[sr][ss + 8] = kv1;
      *(uint4*)&Vs[sr][ss]     = vv0;
      *(uint4*)&Vs[sr][ss + 8] = vv1;
      *(uint4*)&Ms[sr][(t & 3) * 16] = mv;
      __syncthreads();
      bf16x8 aq0 = *(const bf16x8*)&Qs[wave * 16 + l16][quad * 8];
      bf16x8 aq1 = *(const bf16x8*)&Qs[wave * 16 + l16][32 + quad * 8];
      f32x4 S[4];
#pragma unroll
      for (int nt = 0; nt < 4; nt++) {
        bf16x8 bk0 = *(const bf16x8*)&Ks[nt * 16 + l16][quad * 8];
        bf16x8 bk1 = *(const bf16x8*)&Ks[nt * 16 + l16][32 + quad * 8];
        f32x4 sa = {};
        sa = MFMA16(aq0, bk0, sa);
        sa = MFMA16(aq1, bk1, sa);
        S[nt] = sa;
      }
#pragma unroll
      for (int nt = 0; nt < 4; nt++)
#pragma unroll
        for (int r = 0; r < 4; r++) {
          u8 mk = Ms[wave * 16 + quad * 4 + r][nt * 16 + l16];
          float sv = S[nt][r] * 0.125f;            // NORM = 1/sqrt(64)
          S[nt][r] = mk ? sv : -1e30f;             // sentinel for masked
        }
      float mnew[4], alpha[4];
#pragma unroll
      for (int r = 0; r < 4; r++) {
        float rm = fmaxf(fmaxf(S[0][r], S[1][r]), fmaxf(S[2][r], S[3][r]));
        rm = fmaxf(rm, __shfl_xor(rm, 1));
        rm = fmaxf(rm, __shfl_xor(rm, 2));
        rm = fmaxf(rm, __shfl_xor(rm, 4));
        rm = fmaxf(rm, __shfl_xor(rm, 8));
        float mn = fmaxf(mrow[r], rm);
        mnew[r] = mn;
        alpha[r] = __expf(mrow[r] - mn);           // exp(0)=1 when both -1e30: fine
        mrow[r] = mn;
      }
#pragma unroll
      for (int nt = 0; nt < 4; nt++)
#pragma unroll
        for (int r = 0; r < 4; r++) {
          float sv = S[nt][r];
          S[nt][r] = (sv < -1e29f) ? 0.f : __expf(sv - mnew[r]);  // masked -> exactly 0
        }
#pragma unroll
      for (int r = 0; r < 4; r++) {
        float rs = S[0][r] + S[1][r] + S[2][r] + S[3][r];
        rs += __shfl_xor(rs, 1);
        rs += __shfl_xor(rs, 2);
        rs += __shfl_xor(rs, 4);
        rs += __shfl_xor(rs, 8);
        lrow[r] = lrow[r] * alpha[r] + rs;
      }
#pragma unroll
      for (int vt = 0; vt < 4; vt++)
#pragma unroll
        for (int r = 0; r < 4; r++) O[vt][r] *= alpha[r];
      // C-layout -> A-layout round trip through LDS (wave-private rows, no barrier)
#pragma unroll
      for (int nt = 0; nt < 4; nt++)
#pragma unroll
        for (int r = 0; r < 4; r++)
          Ps[wave * 16 + quad * 4 + r][nt * 16 + l16] = f2bf(S[nt][r]);
#pragma unroll
      for (int kc = 0; kc < 2; kc++) {
        bf16x8 ap = *(const bf16x8*)&Ps[wave * 16 + l16][kc * 32 + quad * 8];
#pragma unroll
        for (int vt = 0; vt < 4; vt++) {
          bf16x8 bv = *(const bf16x8*)&Vs[vt * 16 + l16][kc * 32 + quad * 8];
          O[vt] = MFMA16(ap, bv, O[vt]);
        }
      }
    }
    __syncthreads();  // protect Qs restage of next c
  }
#pragma unroll
  for (int vt = 0; vt < 4; vt++)
#pragma unroll
    for (int r = 0; r < 4; r++) {
      float l = lrow[r];
      float val = (l > 0.f) ? O[vt][r] / l : 0.f;
      heads[((size_t)(h * 16 + b) * 512 + q0 + wave * 16 + quad * 4 + r) * 64 + vt * 16 + l16] = f2bf(val);
    }
}

// ---------------------------------------------------------------- pass C: out = heads x W_out
// out(8192 x 512) = heads[(b,q),(h,v)=512] * Wot. 64x64 tile, K-loop over h.
__global__ __launch_bounds__(256) void gemm_out_k(const u16* __restrict__ heads,
                                                  const u16* __restrict__ Wot,
                                                  float* __restrict__ out) {
  __shared__ u16 As[64][72];
  __shared__ u16 Bs[64][72];
  int t = threadIdx.x;
  int wave = t >> 6, lane = t & 63, quad = lane >> 4, l16 = lane & 15;
  int m0 = blockIdx.x * 64, e0 = blockIdx.y * 64;
  int b = m0 >> 9, q0 = m0 & 511;
  f32x4 acc[4] = {};
  int sr = t >> 2, ss = (t & 3) * 16;
  for (int h = 0; h < 8; h++) {
    uint4 a0 = *(const uint4*)(heads + ((size_t)(h * 16 + b) * 512 + q0 + sr) * 64 + ss);
    uint4 a1 = *(const uint4*)(heads + ((size_t)(h * 16 + b) * 512 + q0 + sr) * 64 + ss + 8);
    uint4 b0 = *(const uint4*)(Wot + ((size_t)(h * 512 + e0 + sr)) * 64 + ss);
    uint4 b1 = *(const uint4*)(Wot + ((size_t)(h * 512 + e0 + sr)) * 64 + ss + 8);
    __syncthreads();
    *(uint4*)&As[sr][ss]     = a0;
    *(uint4*)&As[sr][ss + 8] = a1;
    *(uint4*)&Bs[sr][ss]     = b0;
    *(uint4*)&Bs[sr][ss + 8] = b1;
    __syncthreads();
#pragma unroll
    for (int kc = 0; kc < 2; kc++) {
      bf16x8 af = *(const bf16x8*)&As[wave * 16 + l16][kc * 32 + quad * 8];
#pragma unroll
      for (int nt = 0; nt < 4; nt++) {
        bf16x8 bfr = *(const bf16x8*)&Bs[nt * 16 + l16][kc * 32 + quad * 8];
        acc[nt] = MFMA16(af, bfr, acc[nt]);
      }
    }
  }
#pragma unroll
  for (int nt = 0; nt < 4; nt++)
#pragma unroll
    for (int r = 0; r < 4; r++)
      out[((size_t)(b * 512 + q0 + wave * 16 + quad * 4 + r)) * 512 + e0 + nt * 16 + l16] = acc[nt][r];
}

// ---------------------------------------------------------------- launch

extern "C" void kernel_launch(void* const* d_in, const int* in_sizes, int n_in,
                              void* d_out, int out_size, void* d_ws, size_t ws_size,
                              hipStream_t stream) {
  const float* q   = (const float*)d_in[0];
  const int*   att = (const int*)d_in[1];
  const int*   grp = (const int*)d_in[2];
  const int*   sd  = (const int*)d_in[3];
  WPtrs wp;
  for (int j = 0; j < 12; j++) wp.w[j] = (const float*)d_in[4 + j];
  const float* wout = (const float*)d_in[16];

  char* ws = (char*)d_ws;
  // workspace layout (total 141,033,472 B)
  u16* qb    = (u16*)(ws + 0);            //   8,388,608
  u16* Wbt   = (u16*)(ws + 8388608);      //   6,291,456
  u16* Wot   = (u16*)(ws + 14680064);     //     524,288
  u8*  Mpk   = (u8*) (ws + 15204352);     //  16,777,216
  u16* P     = (u16*)(ws + 31981568);     // 100,663,296
  u16* heads = (u16*)(ws + 132644864);    //   8,388,608
  float* out = (float*)d_out;

  prep_masks_k<<<4096, 256, 0, stream>>>(att, grp, sd, Mpk);
  prep_q_k<<<2048, 256, 0, stream>>>(q, qb);
  prep_w_k<<<96, 256, 0, stream>>>(wp, Wbt);
  prep_wout_k<<<8, 256, 0, stream>>>(wout, Wot);
  gemm_proj_k<<<dim3(64, 48), 256, 0, stream>>>(qb, Wbt, P);
  attn_k<<<dim3(8, 16, 8), 256, 0, stream>>>(P, Mpk, heads);
  gemm_out_k<<<dim3(128, 8), 256, 0, stream>>>(heads, Wot, out);
}

// Round 3
// 404.390 us; speedup vs baseline: 1.6055x; 1.5289x over previous
//
#include <hip/hip_runtime.h>

// Problem constants: H=8, B=16, G=512, NQ=512, D=512, KD=VD=64, E=512, NORM=0.125
using u8 = unsigned char;
using u16 = unsigned short;
using u32 = unsigned int;

typedef __attribute__((ext_vector_type(8))) __bf16 bf16x8;
typedef __attribute__((ext_vector_type(4))) float f32x4;

#define MFMA16(A, B, C) __builtin_amdgcn_mfma_f32_16x16x32_bf16((A), (B), (C), 0, 0, 0)

__device__ __forceinline__ u16 f2bf(float f) {
  u32 u = __builtin_bit_cast(u32, f);
  u += 0x7fffu + ((u >> 16) & 1u);   // round-to-nearest-even
  return (u16)(u >> 16);
}

// async 16B/lane global->LDS DMA. lds dest must be wave-uniform base; lane i
// lands at base + i*16.
__device__ __forceinline__ void gl_lds16(const void* g, void* l) {
  __builtin_amdgcn_global_load_lds(
      (const __attribute__((address_space(1))) void*)g,
      (__attribute__((address_space(3))) void*)l, 16, 0, 0);
}

// ---------------------------------------------------------------- prep kernels

__global__ void prep_q_k(const float* __restrict__ q, u16* __restrict__ qb) {
  int idx = blockIdx.x * 256 + threadIdx.x;          // one per 8 elems
  const float4* p = (const float4*)q + (size_t)idx * 2;
  float4 a = p[0], b = p[1];
  u32 w0 = f2bf(a.x) | ((u32)f2bf(a.y) << 16);
  u32 w1 = f2bf(a.z) | ((u32)f2bf(a.w) << 16);
  u32 w2 = f2bf(b.x) | ((u32)f2bf(b.y) << 16);
  u32 w3 = f2bf(b.z) | ((u32)f2bf(b.w) << 16);
  ((uint4*)qb)[idx] = make_uint4(w0, w1, w2, w3);
}

struct WPtrs { const float* w[12]; };

// Wbt[col][d] = W_iw[h][d][kk],  col = iw*512 + h*64 + kk  (K-major for B-fragments)
__global__ void prep_w_k(WPtrs wp, u16* __restrict__ Wbt) {
  int iw = blockIdx.x >> 3;
  int h  = blockIdx.x & 7;
  int kk = threadIdx.x & 63;
  int dd = threadIdx.x >> 6;
  const float* W = wp.w[iw];
  for (int d = dd; d < 512; d += 4) {
    float v = W[((size_t)(h * 512 + d)) * 64 + kk];      // coalesced over kk
    Wbt[((size_t)(iw * 512 + h * 64 + kk)) * 512 + d] = f2bf(v);
  }
}

// Wot[h][e][v] = W_out[h][v][e]
__global__ void prep_wout_k(const float* __restrict__ wout, u16* __restrict__ Wot) {
  int h = blockIdx.x;
  int t = threadIdx.x;
  for (int ee = 0; ee < 2; ee++) {
    int e = ee * 256 + t;
    for (int v = 0; v < 64; v++)
      Wot[((size_t)(h * 512 + e)) * 64 + v] = f2bf(wout[((size_t)(h * 64 + v)) * 512 + e]);
  }
}

// Mpk[b][q][c][g] (uint8 0/1): c0=sparse_dist[b,q,g], c1=att[b,g,q], c2=att[b,q,g], c3=group[b,q,g]
__global__ void prep_masks_k(const int* __restrict__ att, const int* __restrict__ grp,
                             const int* __restrict__ sd, u8* __restrict__ Mpk) {
  int idx = blockIdx.x * 256 + threadIdx.x;  // one per (b,q,4g)
  int g0 = (idx & 127) << 2;
  int q  = (idx >> 7) & 511;
  int b  = idx >> 16;
  size_t rbase = ((size_t)(b * 512 + q)) * 512 + g0;
  int4 v0 = *(const int4*)(sd + rbase);
  int4 v2 = *(const int4*)(att + rbase);
  int4 v3 = *(const int4*)(grp + rbase);
  size_t cb = ((size_t)(b * 512 + g0)) * 512 + q;     // att[b][g][q], strided
  int t0 = att[cb], t1 = att[cb + 512], t2 = att[cb + 1024], t3 = att[cb + 1536];
  size_t ob = (((size_t)(b * 512 + q)) * 4) * 512 + g0;
  auto pk = [](int a, int b2, int c, int d) -> u32 {
    return (a ? 1u : 0u) | ((b2 ? 1u : 0u) << 8) | ((c ? 1u : 0u) << 16) | ((d ? 1u : 0u) << 24);
  };
  *(u32*)(Mpk + ob)        = pk(v0.x, v0.y, v0.z, v0.w);
  *(u32*)(Mpk + ob + 512)  = pk(t0, t1, t2, t3);
  *(u32*)(Mpk + ob + 1024) = pk(v2.x, v2.y, v2.z, v2.w);
  *(u32*)(Mpk + ob + 1536) = pk(v3.x, v3.y, v3.z, v3.w);
}

// ---------------------------------------------------------------- pass A: all 12 projections
// C(8192 x 6144) = qb(8192 x 512) * W(512 x 6144). 128x128 tile, BK=64, 4 waves.
// Staging: global_load_lds 16B/lane into unpadded [128][64] LDS; XOR swizzle
// (chunk' = chunk ^ (row&7)) applied via the per-lane global gather address.
// Q/K classes stored [ihb][n][k]; V class stored transposed [ihb][k][n].
__global__ __launch_bounds__(256) void gemm_proj_k(const u16* __restrict__ qb,
                                                   const u16* __restrict__ Wbt,
                                                   u16* __restrict__ P) {
  __shared__ __align__(16) u16 smem[17408];  // As 8192 | Bs 8192; Cs overlays 128x136
  u16* As = smem;
  u16* Bs = smem + 8192;
  int t = threadIdx.x;
  int wave = t >> 6, lane = t & 63, quad = lane >> 4, l16 = lane & 15;
  int m0w = (wave >> 1) * 64, n0w = (wave & 1) * 64;
  int bm = blockIdx.x, bn = blockIdx.y;
  f32x4 acc[4][4] = {};
  // staging addressing: wave w issue j covers tile rows w*32+j*8 .. +7
  int lr8 = lane >> 3;                 // 0..7
  int lc8 = (lane & 7) ^ lr8;         // swizzled logical chunk to fetch
  const u16* ag = qb  + ((size_t)(bm * 128 + wave * 32 + lr8)) * 512 + lc8 * 8;
  const u16* bg = Wbt + ((size_t)(bn * 128 + wave * 32 + lr8)) * 512 + lc8 * 8;
  u16* Asd = As + wave * 2048;        // wave*4 issues * 512 u16
  u16* Bsd = Bs + wave * 2048;
  for (int k0 = 0; k0 < 512; k0 += 64) {
    __syncthreads();                  // prev tile's LDS reads done
#pragma unroll
    for (int j = 0; j < 4; j++) {
      gl_lds16(ag + (size_t)j * 8 * 512 + k0, Asd + j * 512);
      gl_lds16(bg + (size_t)j * 8 * 512 + k0, Bsd + j * 512);
    }
    __syncthreads();                  // vmcnt(0) drain: tiles resident
#pragma unroll
    for (int kc = 0; kc < 2; kc++) {
      bf16x8 am[4], bnf[4];
#pragma unroll
      for (int i = 0; i < 4; i++) {
        int ca = ((kc * 4 + quad) ^ (l16 & 7)) * 8;
        am[i]  = *(const bf16x8*)&As[(m0w + i * 16 + l16) * 64 + ca];
        bnf[i] = *(const bf16x8*)&Bs[(n0w + i * 16 + l16) * 64 + ca];
      }
#pragma unroll
      for (int mt = 0; mt < 4; mt++)
#pragma unroll
        for (int nt = 0; nt < 4; nt++)
          acc[mt][nt] = MFMA16(am[mt], bnf[nt], acc[mt][nt]);
    }
  }
  // ---------------- epilogue: LDS-staged coalesced stores ----------------
  int iw = bn >> 2;                  // both 64-col groups share iw
  bool isV = (iw % 3) == 2;
  int b  = bm >> 2;
  int n0 = (bm & 3) * 128;
  u16 (*Cs)[136] = (u16(*)[136])smem;  // 128 x 136 u16 = 34816 B
  __syncthreads();
#pragma unroll
  for (int mt = 0; mt < 4; mt++)
#pragma unroll
    for (int nt = 0; nt < 4; nt++)
#pragma unroll
      for (int r = 0; r < 4; r++) {
        int rm = m0w + mt * 16 + quad * 4 + r;
        int cn = n0w + nt * 16 + l16;
        u16 v = f2bf(acc[mt][nt][r]);
        if (!isV) Cs[rm][cn] = v;
        else      Cs[cn][rm] = v;
      }
  __syncthreads();
#pragma unroll
  for (int p = 0; p < 8; p++) {
    int idx = p * 256 + t;
    int seg  = idx & 15;
    int crow = idx >> 4;
    uint4 v = *(const uint4*)&Cs[crow][seg * 8];
    if (!isV) {
      int col = seg * 8;
      int cg = col >> 6, k = col & 63;
      int h = (bn * 2 + cg) & 7;
      u16* dst = P + ((size_t)((iw * 8 + h) * 16 + b)) * 32768 + (size_t)(n0 + crow) * 64 + k;
      *(uint4*)dst = v;
    } else {
      int cg = crow >> 6, k = crow & 63;
      int h = (bn * 2 + cg) & 7;
      u16* dst = P + ((size_t)((iw * 8 + h) * 16 + b)) * 32768 + (size_t)k * 512 + n0 + seg * 8;
      *(uint4*)dst = v;
    }
  }
}

// ---------------------------------------------------------------- pass B: fused masked attention
// grid (qt=8, b=16, h=8); block 256 = 4 waves, each wave owns 16 q-rows.
// Max-free single-pass softmax (|s| << 88 so exp can't overflow); per-lane
// denominator accumulation, one cross-lane reduce at epilogue.
__global__ __launch_bounds__(256) void attn_k(const u16* __restrict__ P,
                                              const u8* __restrict__ Mpk,
                                              u16* __restrict__ heads) {
  __shared__ __align__(16) u16 Qs[4096];   // [64][64] swizzled
  __shared__ __align__(16) u16 Ks[4096];
  __shared__ __align__(16) u16 Vs[4096];   // [v][g] swizzled
  __shared__ __align__(16) u16 Ps[64][72]; // padded (per-lane b16 writes)
  __shared__ __align__(16) u8  Ms[4096];   // [64][64]
  int t = threadIdx.x;
  int wave = t >> 6, lane = t & 63, quad = lane >> 4, l16 = lane & 15;
  int qt = blockIdx.x, b = blockIdx.y, h = blockIdx.z;
  int q0 = qt * 64;
  int lr8 = lane >> 3, lc8 = (lane & 7) ^ lr8;     // 128B-row tiles
  int mr4 = lane >> 2, mc4 = lane & 3;             // 64B-row mask tile
  float lrow[4] = {0.f, 0.f, 0.f, 0.f};
  f32x4 O[4] = {};

  auto issueKVM = [&](int c, int g0) {
    const u16* PK = P + ((size_t)((3 * c + 1) * 8 + h) * 16 + b) * 32768;
    const u16* PV = P + ((size_t)((3 * c + 2) * 8 + h) * 16 + b) * 32768;
#pragma unroll
    for (int j = 0; j < 2; j++) {
      gl_lds16(PK + (size_t)(g0 + wave * 16 + j * 8 + lr8) * 64 + lc8 * 8,
               Ks + wave * 1024 + j * 512);
      gl_lds16(PV + (size_t)(wave * 16 + j * 8 + lr8) * 512 + g0 + lc8 * 8,
               Vs + wave * 1024 + j * 512);
    }
    gl_lds16(Mpk + ((size_t)(b * 512 + q0 + wave * 16 + mr4) * 4 + c) * 512 + g0 + mc4 * 16,
             Ms + wave * 1024);
  };

  for (int c = 0; c < 4; c++) {
    const u16* PQ = P + ((size_t)((3 * c + 0) * 8 + h) * 16 + b) * 32768;
    __syncthreads();                 // all LDS reads from previous iter done
#pragma unroll
    for (int j = 0; j < 2; j++)
      gl_lds16(PQ + (size_t)(q0 + wave * 16 + j * 8 + lr8) * 64 + lc8 * 8,
               Qs + wave * 1024 + j * 512);
    issueKVM(c, 0);
    for (int gt = 0; gt < 8; gt++) {
      __syncthreads();               // drain DMA: tiles resident
      bf16x8 aq0 = *(const bf16x8*)&Qs[(wave * 16 + l16) * 64 + ((quad) ^ (l16 & 7)) * 8];
      bf16x8 aq1 = *(const bf16x8*)&Qs[(wave * 16 + l16) * 64 + ((4 + quad) ^ (l16 & 7)) * 8];
      f32x4 S[4];
#pragma unroll
      for (int nt = 0; nt < 4; nt++) {
        bf16x8 bk0 = *(const bf16x8*)&Ks[(nt * 16 + l16) * 64 + ((quad) ^ (l16 & 7)) * 8];
        bf16x8 bk1 = *(const bf16x8*)&Ks[(nt * 16 + l16) * 64 + ((4 + quad) ^ (l16 & 7)) * 8];
        f32x4 sa = {};
        sa = MFMA16(aq0, bk0, sa);
        sa = MFMA16(aq1, bk1, sa);
        S[nt] = sa;
      }
#pragma unroll
      for (int nt = 0; nt < 4; nt++)
#pragma unroll
        for (int r = 0; r < 4; r++) {
          u8 mk = Ms[(wave * 16 + quad * 4 + r) * 64 + nt * 16 + l16];
          float e = mk ? __expf(S[nt][r] * 0.125f) : 0.f;   // NORM=0.125; no max needed
          lrow[r] += e;
          u32 u = __builtin_bit_cast(u32, e);
          Ps[wave * 16 + quad * 4 + r][nt * 16 + l16] = (u16)((u + 0x8000u) >> 16);
        }
#pragma unroll
      for (int kc = 0; kc < 2; kc++) {
        bf16x8 ap = *(const bf16x8*)&Ps[wave * 16 + l16][kc * 32 + quad * 8];
#pragma unroll
        for (int vt = 0; vt < 4; vt++) {
          bf16x8 bv = *(const bf16x8*)&Vs[(vt * 16 + l16) * 64 + ((kc * 4 + quad) ^ (l16 & 7)) * 8];
          O[vt] = MFMA16(ap, bv, O[vt]);
        }
      }
      if (gt < 7) {
        __syncthreads();             // compute reads done before restage
        issueKVM(c, (gt + 1) * 64);
      }
    }
  }
  float lr[4];
#pragma unroll
  for (int r = 0; r < 4; r++) {
    float l = lrow[r];
    l += __shfl_xor(l, 1);
    l += __shfl_xor(l, 2);
    l += __shfl_xor(l, 4);
    l += __shfl_xor(l, 8);
    lr[r] = l;
  }
#pragma unroll
  for (int vt = 0; vt < 4; vt++)
#pragma unroll
    for (int r = 0; r < 4; r++) {
      float l = lr[r];
      float val = (l > 0.f) ? O[vt][r] / l : 0.f;
      heads[((size_t)(h * 16 + b) * 512 + q0 + wave * 16 + quad * 4 + r) * 64 + vt * 16 + l16] = f2bf(val);
    }
}

// ---------------------------------------------------------------- pass C: out = heads x W_out
// out(8192 x 512) = heads[(b,q),(h,v)=512] * Wot. 64x64 tile, K-loop over h.
__global__ __launch_bounds__(256) void gemm_out_k(const u16* __restrict__ heads,
                                                  const u16* __restrict__ Wot,
                                                  float* __restrict__ out) {
  __shared__ __align__(16) u16 As[4096];
  __shared__ __align__(16) u16 Bs[4096];
  int t = threadIdx.x;
  int wave = t >> 6, lane = t & 63, quad = lane >> 4, l16 = lane & 15;
  int m0 = blockIdx.x * 64, e0 = blockIdx.y * 64;
  int b = m0 >> 9, q0 = m0 & 511;
  int lr8 = lane >> 3, lc8 = (lane & 7) ^ lr8;
  f32x4 acc[4] = {};
  for (int h = 0; h < 8; h++) {
    __syncthreads();
#pragma unroll
    for (int j = 0; j < 2; j++) {
      gl_lds16(heads + ((size_t)(h * 16 + b) * 512 + q0 + wave * 16 + j * 8 + lr8) * 64 + lc8 * 8,
               As + wave * 1024 + j * 512);
      gl_lds16(Wot + ((size_t)(h * 512 + e0 + wave * 16 + j * 8 + lr8)) * 64 + lc8 * 8,
               Bs + wave * 1024 + j * 512);
    }
    __syncthreads();
#pragma unroll
    for (int kc = 0; kc < 2; kc++) {
      bf16x8 af = *(const bf16x8*)&As[(wave * 16 + l16) * 64 + ((kc * 4 + quad) ^ (l16 & 7)) * 8];
#pragma unroll
      for (int nt = 0; nt < 4; nt++) {
        bf16x8 bfr = *(const bf16x8*)&Bs[(nt * 16 + l16) * 64 + ((kc * 4 + quad) ^ (l16 & 7)) * 8];
        acc[nt] = MFMA16(af, bfr, acc[nt]);
      }
    }
  }
#pragma unroll
  for (int nt = 0; nt < 4; nt++)
#pragma unroll
    for (int r = 0; r < 4; r++)
      out[((size_t)(b * 512 + q0 + wave * 16 + quad * 4 + r)) * 512 + e0 + nt * 16 + l16] = acc[nt][r];
}

// ---------------------------------------------------------------- launch

extern "C" void kernel_launch(void* const* d_in, const int* in_sizes, int n_in,
                              void* d_out, int out_size, void* d_ws, size_t ws_size,
                              hipStream_t stream) {
  const float* q   = (const float*)d_in[0];
  const int*   att = (const int*)d_in[1];
  const int*   grp = (const int*)d_in[2];
  const int*   sd  = (const int*)d_in[3];
  WPtrs wp;
  for (int j = 0; j < 12; j++) wp.w[j] = (const float*)d_in[4 + j];
  const float* wout = (const float*)d_in[16];

  char* ws = (char*)d_ws;
  // workspace layout (total 141,033,472 B)
  u16* qb    = (u16*)(ws + 0);            //   8,388,608
  u16* Wbt   = (u16*)(ws + 8388608);      //   6,291,456
  u16* Wot   = (u16*)(ws + 14680064);     //     524,288
  u8*  Mpk   = (u8*) (ws + 15204352);     //  16,777,216
  u16* P     = (u16*)(ws + 31981568);     // 100,663,296
  u16* heads = (u16*)(ws + 132644864);    //   8,388,608
  float* out = (float*)d_out;

  prep_masks_k<<<4096, 256, 0, stream>>>(att, grp, sd, Mpk);
  prep_q_k<<<2048, 256, 0, stream>>>(q, qb);
  prep_w_k<<<96, 256, 0, stream>>>(wp, Wbt);
  prep_wout_k<<<8, 256, 0, stream>>>(wout, Wot);
  gemm_proj_k<<<dim3(64, 48), 256, 0, stream>>>(qb, Wbt, P);
  attn_k<<<dim3(8, 16, 8), 256, 0, stream>>>(P, Mpk, heads);
  gemm_out_k<<<dim3(128, 8), 256, 0, stream>>>(heads, Wot, out);
}